// Round 4
// baseline (889.111 us; speedup 1.0000x reference)
//
#include <hip/hip_runtime.h>
#include <hip/hip_fp16.h>
#include <math.h>

#define NXY 320
#define NC 20
#define NT 25
#define NPIX 102400   // 320*320
#define PI_F 3.14159265358979f
#define TWOPI_F 6.28318530717959f

__device__ __forceinline__ float2 cmul(float2 a, float2 b) {
    return make_float2(a.x * b.x - a.y * b.y, a.x * b.y + a.y * b.x);
}

// Per-lane FFT twiddles — invariant across every FFT a thread performs.
struct Tw {
    float2 st[6];   // stage twiddle: (1,0) lower half, e^{+i*pi*i/h} upper
    float  sgn[6];  // +1 lower, -1 upper
    float2 w5[5];   // w5[r] = e^{+2*pi*i * r*J / 320}
    int J;          // bitrev6(lane)
};

__device__ __forceinline__ void tw_init(Tw& t) {
    const int lane = threadIdx.x & 63;
    #pragma unroll
    for (int s = 0; s < 6; ++s) {
        const int h = 32 >> s;
        const bool up = (lane & h) != 0;
        t.sgn[s] = up ? -1.0f : 1.0f;
        if (up) {
            float ss, cc;
            __sincosf(PI_F * (float)(lane & (h - 1)) / (float)h, &ss, &cc);
            t.st[s] = make_float2(cc, ss);
        } else {
            t.st[s] = make_float2(1.0f, 0.0f);
        }
    }
    t.J = (int)(__brev((unsigned)lane) >> 26);
    t.w5[0] = make_float2(1.0f, 0.0f);
    #pragma unroll
    for (int r = 1; r < 5; ++r) {
        float ss, cc;
        __sincosf(TWOPI_F * (float)(r * t.J) / 320.0f, &ss, &cc);
        t.w5[r] = make_float2(cc, ss);
    }
}

// K interleaved 320-point DFTs (+i sign) by one wave.
// x[k][r] = seq_k[5*lane + r] in; out[k][s5] = X_k[J + 64*s5].
template <int K>
__device__ __forceinline__ void fft320xK(const Tw& t, float2 (&x)[K][5], float2 (&out)[K][5]) {
    #pragma unroll
    for (int s = 0; s < 6; ++s) {
        const int h = 32 >> s;
        #pragma unroll
        for (int r = 0; r < 5; ++r) {
            #pragma unroll
            for (int k = 0; k < K; ++k) {
                float ox = __shfl_xor(x[k][r].x, h);
                float oy = __shfl_xor(x[k][r].y, h);
                float dx = fmaf(t.sgn[s], x[k][r].x, ox);
                float dy = fmaf(t.sgn[s], x[k][r].y, oy);
                x[k][r].x = dx * t.st[s].x - dy * t.st[s].y;
                x[k][r].y = dx * t.st[s].y + dy * t.st[s].x;
            }
        }
    }
    const float W5x[5] = {1.0f, 0.309016994f, -0.809016994f, -0.809016994f, 0.309016994f};
    const float W5y[5] = {0.0f, 0.951056516f, 0.587785252f, -0.587785252f, -0.951056516f};
    #pragma unroll
    for (int k = 0; k < K; ++k) {
        float2 T[5];
        T[0] = x[k][0];
        #pragma unroll
        for (int r = 1; r < 5; ++r) T[r] = cmul(x[k][r], t.w5[r]);
        #pragma unroll
        for (int s5 = 0; s5 < 5; ++s5) {
            float2 acc = T[0];
            #pragma unroll
            for (int r = 1; r < 5; ++r) {
                const int kk = (r * s5) % 5;
                acc.x += T[r].x * W5x[kk] - T[r].y * W5y[kk];
                acc.y += T[r].x * W5y[kk] + T[r].y * W5x[kk];
            }
            out[k][s5] = acc;
        }
    }
}

// smapsC[c][p] = conj(smaps[p][c]) * (-1)^(m+n) / 320   (fp32 staging table)
__global__ __launch_bounds__(256) void k_prep_smaps(const float* __restrict__ smr,
                                                    const float* __restrict__ smi,
                                                    float2* __restrict__ smapsC) {
    const int p0 = blockIdx.x * 64;
    __shared__ float s_r[64 * 21];
    __shared__ float s_i[64 * 21];
    for (int j = threadIdx.x; j < 64 * NC; j += blockDim.x) {
        int p = j / NC, c = j - p * NC;
        s_r[p * 21 + c] = smr[(size_t)p0 * NC + j];
        s_i[p * 21 + c] = smi[(size_t)p0 * NC + j];
    }
    __syncthreads();
    for (int j = threadIdx.x; j < 64 * NC; j += blockDim.x) {
        int c = j >> 6, p = j & 63;
        int pg = p0 + p;
        int m = pg / NXY, n = pg - m * NXY;
        float sgn = (((m + n) & 1) ? -1.0f : 1.0f) * (1.0f / 320.0f);
        smapsC[(size_t)c * NPIX + pg] = make_float2(s_r[p * 21 + c] * sgn,
                                                    -s_i[p * 21 + c] * sgn);
    }
}

// smapsP[((c*320 + v)*5 + s5)*64 + lane] = smapsC[c][(bitrev6(lane)+64*s5)*320 + v] (half2)
__global__ __launch_bounds__(256) void k_perm_smaps(const float2* __restrict__ smapsC,
                                                    __half2* __restrict__ smapsP) {
    const int c = blockIdx.x;
    const int s5 = blockIdx.y;
    const int v0 = blockIdx.z * 64;
    __shared__ __half2 t2[64 * 65];
    for (int j = threadIdx.x; j < 64 * 64; j += blockDim.x) {
        int ur = j >> 6, vc = j & 63;
        float2 v = smapsC[(size_t)c * NPIX + (size_t)(s5 * 64 + ur) * NXY + v0 + vc];
        t2[ur * 65 + vc] = __floats2half2_rn(v.x, v.y);
    }
    __syncthreads();
    for (int j = threadIdx.x; j < 64 * 64; j += blockDim.x) {
        int vr = j >> 6, lane = j & 63;
        int J = (int)(__brev((unsigned)lane) >> 26);
        smapsP[(size_t)((c * NXY + v0 + vr) * 5 + s5) * 64 + lane] = t2[J * 65 + vr];
    }
}

// ksS[c][p] = (ksr + i*ksi)(p,c) * (-1)^(m+n)   (half2, pre-mask)
__global__ __launch_bounds__(256) void k_prep_ks(const float* __restrict__ ksr,
                                                 const float* __restrict__ ksi,
                                                 __half2* __restrict__ ksS) {
    const int p0 = blockIdx.x * 64;
    __shared__ float s_r[64 * 21];
    __shared__ float s_i[64 * 21];
    for (int j = threadIdx.x; j < 64 * NC; j += blockDim.x) {
        int p = j / NC, c = j - p * NC;
        s_r[p * 21 + c] = ksr[(size_t)p0 * NC + j];
        s_i[p * 21 + c] = ksi[(size_t)p0 * NC + j];
    }
    __syncthreads();
    for (int j = threadIdx.x; j < 64 * NC; j += blockDim.x) {
        int c = j >> 6, p = j & 63;
        int pg = p0 + p;
        int m = pg / NXY, n = pg - m * NXY;
        float sgn = ((m + n) & 1) ? -1.0f : 1.0f;
        ksS[(size_t)c * NPIX + pg] =
            __floats2half2_rn(s_r[p * 21 + c] * sgn, s_i[p * 21 + c] * sgn);
    }
}

// FUSED: mask*kspace + row FFTs (over n). One block = 16 rows of one (c,tc).
// blockIdx.x = q (all (c,t) of one chunk — x-fastest dispatch keeps the mask
// slab of a given mtile L3-resident across its 20*G consumer blocks).
// Each wave does 4 rows interleaved (K=4 ILP). Z[q][v][m], m contiguous.
__global__ __launch_bounds__(256) void k_fft_rows(const float* __restrict__ mask,
                                                  const __half2* __restrict__ ksS,
                                                  __half2* __restrict__ Z,
                                                  int t0, int G) {
    const int q = blockIdx.x;       // c*G + tc
    const int mtile = blockIdx.y;   // 0..19
    const int c = q / G;            // once per block (scalar)
    const int tc = q - c * G;
    const int cq = c * NT + t0 + tc;
    const int wave = threadIdx.x >> 6;
    const int lane = threadIdx.x & 63;
    const int m0 = mtile * 16;
    __shared__ __half2 tile[NXY * 17];  // [v][16 + 1 pad]
    Tw t;
    tw_init(t);
    const __half2* ks_c = ksS + (size_t)c * NPIX;
    const float* mk_c = mask + (size_t)cq;
    float2 x[4][5], out[4][5];
    #pragma unroll
    for (int k = 0; k < 4; ++k) {
        const int pbase = (m0 + wave + 4 * k) * NXY + lane * 5;
        const __half2* kp = ks_c + pbase;
        const float* mp = mk_c + (size_t)pbase * (NC * NT);
        #pragma unroll
        for (int r = 0; r < 5; ++r) {
            float2 kv = __half22float2(kp[r]);
            float mkv = mp[(size_t)r * (NC * NT)];
            x[k][r] = make_float2(kv.x * mkv, kv.y * mkv);
        }
    }
    fft320xK<4>(t, x, out);
    #pragma unroll
    for (int k = 0; k < 4; ++k) {
        const int mm = wave + 4 * k;
        #pragma unroll
        for (int s5 = 0; s5 < 5; ++s5) {
            int v = t.J + 64 * s5;
            tile[v * 17 + mm] = __floats2half2_rn(out[k][s5].x, out[k][s5].y);
        }
    }
    __syncthreads();
    __half2* dst = Z + (size_t)q * NPIX + m0;
    for (int j = threadIdx.x; j < NXY * 16; j += blockDim.x) {
        int mm = j & 15, v = j >> 4;
        dst[(size_t)v * NXY + mm] = tile[v * 17 + mm];
    }
}

// Column FFTs (over m) + coil combine; K=2 ILP (two v's per wave), coils split
// across blockIdx.z (2 halves of 10), fp16 partial images imtP[half][t][u][v].
__global__ __launch_bounds__(256) void k_fft_cols_combine(const __half2* __restrict__ Z,
                                                          const __half2* __restrict__ smapsP,
                                                          __half2* __restrict__ imtP,
                                                          int t0, int G) {
    const int vtile = blockIdx.x;   // 0..39
    const int tc = blockIdx.y;
    const int half = blockIdx.z;    // 0/1 -> coils [10h, 10h+10)
    const int wave = threadIdx.x >> 6;
    const int lane = threadIdx.x & 63;
    const int v0 = vtile * 8;
    const int vA = v0 + wave;
    const int vB = v0 + 4 + wave;
    __shared__ __half2 tile[NXY * 9];   // [u][8 v + 1 pad]
    Tw t;
    tw_init(t);
    float2 acc[2][5];
    #pragma unroll
    for (int k = 0; k < 2; ++k)
        #pragma unroll
        for (int s5 = 0; s5 < 5; ++s5) acc[k][s5] = make_float2(0.f, 0.f);
    const int c0 = half * 10;
    for (int c = c0; c < c0 + 10; ++c) {
        const __half2* zc = Z + (size_t)(c * G + tc) * NPIX;
        float2 x[2][5], out[2][5];
        const __half2* colA = zc + (size_t)vA * NXY + lane * 5;
        const __half2* colB = zc + (size_t)vB * NXY + lane * 5;
        #pragma unroll
        for (int r = 0; r < 5; ++r) {
            x[0][r] = __half22float2(colA[r]);
            x[1][r] = __half22float2(colB[r]);
        }
        fft320xK<2>(t, x, out);
        const __half2* spA = smapsP + (size_t)((c * NXY + vA) * 5) * 64 + lane;
        const __half2* spB = smapsP + (size_t)((c * NXY + vB) * 5) * 64 + lane;
        #pragma unroll
        for (int s5 = 0; s5 < 5; ++s5) {
            float2 smA = __half22float2(spA[s5 * 64]);
            float2 smB = __half22float2(spB[s5 * 64]);
            float2 ta = cmul(out[0][s5], smA);
            float2 tb = cmul(out[1][s5], smB);
            acc[0][s5].x += ta.x; acc[0][s5].y += ta.y;
            acc[1][s5].x += tb.x; acc[1][s5].y += tb.y;
        }
    }
    #pragma unroll
    for (int s5 = 0; s5 < 5; ++s5) {
        int u = t.J + 64 * s5;
        tile[u * 9 + wave] = __floats2half2_rn(acc[0][s5].x, acc[0][s5].y);
        tile[u * 9 + 4 + wave] = __floats2half2_rn(acc[1][s5].x, acc[1][s5].y);
    }
    __syncthreads();
    __half2* dst = imtP + (size_t)(half * NT + t0 + tc) * NPIX + v0;
    for (int j = threadIdx.x; j < NXY * 8; j += blockDim.x) {
        int vv = j & 7, u = j >> 3;
        dst[(size_t)u * NXY + vv] = tile[u * 9 + vv];
    }
}

// Bilinear warp + sum over t; reduces the two coil-half partials.
__global__ __launch_bounds__(256) void k_warp_sum(const __half2* __restrict__ imtP,
                                                  const float* __restrict__ flow,
                                                  float* __restrict__ out) {
    const int p0 = blockIdx.x * 256;
    const int tid = threadIdx.x;
    __shared__ float s_fl[2 * NT * 257];
    for (int j = tid; j < 256 * 50; j += 256) {
        int pp = j / 50, rem = j - pp * 50;
        int d = rem / 25, tt = rem - d * 25;
        s_fl[(d * NT + tt) * 257 + pp] = flow[(size_t)p0 * 50 + j];
    }
    __syncthreads();
    const int p = p0 + tid;
    const int x = p / NXY, y = p - x * NXY;
    const float fx = (float)x, fy = (float)y;
    float ar = 0.f, ai = 0.f;
    for (int t = 0; t < NT; ++t) {
        float u = s_fl[t * 257 + tid];
        float v = s_fl[(NT + t) * 257 + tid];
        float xs = fminf(fmaxf(fx + u, 0.0f), 319.0f);
        float ys = fminf(fmaxf(fy + v, 0.0f), 319.0f);
        float x0f = floorf(xs), y0f = floorf(ys);
        int x0 = (int)x0f, y0 = (int)y0f;
        int x1 = min(x0 + 1, NXY - 1), y1 = min(y0 + 1, NXY - 1);
        float wx = xs - x0f, wy = ys - y0f;
        const __half2* b0 = imtP + (size_t)t * NPIX;
        const __half2* b1 = imtP + (size_t)(NT + t) * NPIX;
        int i00 = x0 * NXY + y0, i01 = x0 * NXY + y1;
        int i10 = x1 * NXY + y0, i11 = x1 * NXY + y1;
        float2 c00 = __half22float2(b0[i00]); float2 d00 = __half22float2(b1[i00]);
        float2 c01 = __half22float2(b0[i01]); float2 d01 = __half22float2(b1[i01]);
        float2 c10 = __half22float2(b0[i10]); float2 d10 = __half22float2(b1[i10]);
        float2 c11 = __half22float2(b0[i11]); float2 d11 = __half22float2(b1[i11]);
        c00.x += d00.x; c00.y += d00.y;
        c01.x += d01.x; c01.y += d01.y;
        c10.x += d10.x; c10.y += d10.y;
        c11.x += d11.x; c11.y += d11.y;
        float w00 = (1.f - wx) * (1.f - wy), w01 = (1.f - wx) * wy;
        float w10 = wx * (1.f - wy), w11 = wx * wy;
        ar += c00.x * w00 + c01.x * w01 + c10.x * w10 + c11.x * w11;
        ai += c00.y * w00 + c01.y * w01 + c10.y * w10 + c11.y * w11;
    }
    out[p] = ar;
    out[NPIX + p] = ai;
}

extern "C" void kernel_launch(void* const* d_in, const int* in_sizes, int n_in,
                              void* d_out, int out_size, void* d_ws, size_t ws_size,
                              hipStream_t stream) {
    const float* ksr = (const float*)d_in[0];
    const float* ksi = (const float*)d_in[1];
    const float* mask = (const float*)d_in[2];
    const float* smr = (const float*)d_in[3];
    const float* smi = (const float*)d_in[4];
    const float* flow = (const float*)d_in[5];
    float* out = (float*)d_out;

    char* ws = (char*)d_ws;
    const size_t smapsC_bytes = (size_t)NC * NPIX * sizeof(float2);          // 16.4 MB
    const size_t smapsP_bytes = (size_t)NC * NPIX * sizeof(__half2);         // 8.2 MB
    const size_t ksS_bytes = (size_t)NC * NPIX * sizeof(__half2);            // 8.2 MB
    const size_t imtP_bytes = (size_t)2 * NT * NPIX * sizeof(__half2);       // 20.5 MB
    const size_t fixed = smapsC_bytes + smapsP_bytes + ksS_bytes + imtP_bytes;
    const size_t per_t = (size_t)NC * NPIX * sizeof(__half2);                // Z: 8.2 MB

    int G = 1;
    if (ws_size > fixed + per_t) {
        size_t g = (ws_size - fixed) / per_t;
        G = (int)(g > (size_t)NT ? (size_t)NT : g);
    }
    if (G < 1) G = 1;

    float2* smapsC = (float2*)ws;
    __half2* smapsP = (__half2*)(ws + smapsC_bytes);
    __half2* ksS = (__half2*)(ws + smapsC_bytes + smapsP_bytes);
    __half2* imtP = (__half2*)(ws + smapsC_bytes + smapsP_bytes + ksS_bytes);
    __half2* Z = (__half2*)(ws + fixed);

    k_prep_smaps<<<NPIX / 64, 256, 0, stream>>>(smr, smi, smapsC);
    k_perm_smaps<<<dim3(NC, 5, 5), 256, 0, stream>>>(smapsC, smapsP);
    k_prep_ks<<<NPIX / 64, 256, 0, stream>>>(ksr, ksi, ksS);
    for (int t0 = 0; t0 < NT; t0 += G) {
        int g = (NT - t0) < G ? (NT - t0) : G;
        k_fft_rows<<<dim3(NC * g, 20), 256, 0, stream>>>(mask, ksS, Z, t0, g);
        k_fft_cols_combine<<<dim3(40, g, 2), 256, 0, stream>>>(Z, smapsP, imtP, t0, g);
    }
    k_warp_sum<<<NPIX / 256, 256, 0, stream>>>(imtP, flow, out);
}

// Round 5
// 740.770 us; speedup vs baseline: 1.2003x; 1.2003x over previous
//
#include <hip/hip_runtime.h>
#include <hip/hip_fp16.h>
#include <math.h>

#define NXY 320
#define NC 20
#define NT 25
#define NPIX 102400   // 320*320
#define PI_F 3.14159265358979f
#define TWOPI_F 6.28318530717959f

__device__ __forceinline__ float2 cmul(float2 a, float2 b) {
    return make_float2(a.x * b.x - a.y * b.y, a.x * b.y + a.y * b.x);
}

// Per-lane FFT twiddles — invariant across every FFT a thread performs.
struct Tw {
    float2 st[6];   // stage twiddle: (1,0) lower half, e^{+i*pi*i/h} upper
    float  sgn[6];  // +1 lower, -1 upper
    float2 w5[5];   // w5[r] = e^{+2*pi*i * r*J / 320}
    int J;          // bitrev6(lane)
};

__device__ __forceinline__ void tw_init(Tw& t) {
    const int lane = threadIdx.x & 63;
    #pragma unroll
    for (int s = 0; s < 6; ++s) {
        const int h = 32 >> s;
        const bool up = (lane & h) != 0;
        t.sgn[s] = up ? -1.0f : 1.0f;
        if (up) {
            float ss, cc;
            __sincosf(PI_F * (float)(lane & (h - 1)) / (float)h, &ss, &cc);
            t.st[s] = make_float2(cc, ss);
        } else {
            t.st[s] = make_float2(1.0f, 0.0f);
        }
    }
    t.J = (int)(__brev((unsigned)lane) >> 26);
    t.w5[0] = make_float2(1.0f, 0.0f);
    #pragma unroll
    for (int r = 1; r < 5; ++r) {
        float ss, cc;
        __sincosf(TWOPI_F * (float)(r * t.J) / 320.0f, &ss, &cc);
        t.w5[r] = make_float2(cc, ss);
    }
}

// K interleaved 320-point DFTs (+i sign) by one wave.
template <int K>
__device__ __forceinline__ void fft320xK(const Tw& t, float2 (&x)[K][5], float2 (&out)[K][5]) {
    #pragma unroll
    for (int s = 0; s < 6; ++s) {
        const int h = 32 >> s;
        #pragma unroll
        for (int r = 0; r < 5; ++r) {
            #pragma unroll
            for (int k = 0; k < K; ++k) {
                float ox = __shfl_xor(x[k][r].x, h);
                float oy = __shfl_xor(x[k][r].y, h);
                float dx = fmaf(t.sgn[s], x[k][r].x, ox);
                float dy = fmaf(t.sgn[s], x[k][r].y, oy);
                x[k][r].x = dx * t.st[s].x - dy * t.st[s].y;
                x[k][r].y = dx * t.st[s].y + dy * t.st[s].x;
            }
        }
    }
    const float W5x[5] = {1.0f, 0.309016994f, -0.809016994f, -0.809016994f, 0.309016994f};
    const float W5y[5] = {0.0f, 0.951056516f, 0.587785252f, -0.587785252f, -0.951056516f};
    #pragma unroll
    for (int k = 0; k < K; ++k) {
        float2 T[5];
        T[0] = x[k][0];
        #pragma unroll
        for (int r = 1; r < 5; ++r) T[r] = cmul(x[k][r], t.w5[r]);
        #pragma unroll
        for (int s5 = 0; s5 < 5; ++s5) {
            float2 acc = T[0];
            #pragma unroll
            for (int r = 1; r < 5; ++r) {
                const int kk = (r * s5) % 5;
                acc.x += T[r].x * W5x[kk] - T[r].y * W5y[kk];
                acc.y += T[r].x * W5y[kk] + T[r].y * W5x[kk];
            }
            out[k][s5] = acc;
        }
    }
}

// smapsC[c][p] = conj(smaps[p][c]) * (-1)^(m+n) / 320   (fp32 staging table)
__global__ __launch_bounds__(256) void k_prep_smaps(const float* __restrict__ smr,
                                                    const float* __restrict__ smi,
                                                    float2* __restrict__ smapsC) {
    const int p0 = blockIdx.x * 64;
    __shared__ float s_r[64 * 21];
    __shared__ float s_i[64 * 21];
    for (int j = threadIdx.x; j < 64 * NC; j += blockDim.x) {
        int p = j / NC, c = j - p * NC;
        s_r[p * 21 + c] = smr[(size_t)p0 * NC + j];
        s_i[p * 21 + c] = smi[(size_t)p0 * NC + j];
    }
    __syncthreads();
    for (int j = threadIdx.x; j < 64 * NC; j += blockDim.x) {
        int c = j >> 6, p = j & 63;
        int pg = p0 + p;
        int m = pg / NXY, n = pg - m * NXY;
        float sgn = (((m + n) & 1) ? -1.0f : 1.0f) * (1.0f / 320.0f);
        smapsC[(size_t)c * NPIX + pg] = make_float2(s_r[p * 21 + c] * sgn,
                                                    -s_i[p * 21 + c] * sgn);
    }
}

// smapsP[((c*320 + v)*5 + s5)*64 + lane] = smapsC[c][(bitrev6(lane)+64*s5)*320 + v] (half2)
__global__ __launch_bounds__(256) void k_perm_smaps(const float2* __restrict__ smapsC,
                                                    __half2* __restrict__ smapsP) {
    const int c = blockIdx.x;
    const int s5 = blockIdx.y;
    const int v0 = blockIdx.z * 64;
    __shared__ __half2 t2[64 * 65];
    for (int j = threadIdx.x; j < 64 * 64; j += blockDim.x) {
        int ur = j >> 6, vc = j & 63;
        float2 v = smapsC[(size_t)c * NPIX + (size_t)(s5 * 64 + ur) * NXY + v0 + vc];
        t2[ur * 65 + vc] = __floats2half2_rn(v.x, v.y);
    }
    __syncthreads();
    for (int j = threadIdx.x; j < 64 * 64; j += blockDim.x) {
        int vr = j >> 6, lane = j & 63;
        int J = (int)(__brev((unsigned)lane) >> 26);
        smapsP[(size_t)((c * NXY + v0 + vr) * 5 + s5) * 64 + lane] = t2[J * 65 + vr];
    }
}

// ksS[c][p] = (ksr + i*ksi)(p,c) * (-1)^(m+n)   (half2, pre-mask)
__global__ __launch_bounds__(256) void k_prep_ks(const float* __restrict__ ksr,
                                                 const float* __restrict__ ksi,
                                                 __half2* __restrict__ ksS) {
    const int p0 = blockIdx.x * 64;
    __shared__ float s_r[64 * 21];
    __shared__ float s_i[64 * 21];
    for (int j = threadIdx.x; j < 64 * NC; j += blockDim.x) {
        int p = j / NC, c = j - p * NC;
        s_r[p * 21 + c] = ksr[(size_t)p0 * NC + j];
        s_i[p * 21 + c] = ksi[(size_t)p0 * NC + j];
    }
    __syncthreads();
    for (int j = threadIdx.x; j < 64 * NC; j += blockDim.x) {
        int c = j >> 6, p = j & 63;
        int pg = p0 + p;
        int m = pg / NXY, n = pg - m * NXY;
        float sgn = ((m + n) & 1) ? -1.0f : 1.0f;
        ksS[(size_t)c * NPIX + pg] =
            __floats2half2_rn(s_r[p * 21 + c] * sgn, s_i[p * 21 + c] * sgn);
    }
}

// Dense transpose: maskT[(c*G+tc)][p] = (half)mask[p][c*25 + t0 + tc].
// Block = 64 p x G tc of one coil. Reads coalesced fp32; writes 4 halfs
// (8 B) per thread -> 128-B runs per tc row.
__global__ __launch_bounds__(256) void k_transpose_mask(const float* __restrict__ mask,
                                                        __half* __restrict__ maskT,
                                                        int t0, int G) {
    const int p0 = blockIdx.x * 64;
    const int c = blockIdx.y;
    __shared__ float tile[64 * 26];
    if (G == NT) {
        for (int j = threadIdx.x; j < 64 * NT; j += 256) {
            int pl = j / NT, tc = j - pl * NT;  // compile-time divisor
            tile[pl * 26 + tc] = mask[(size_t)(p0 + pl) * (NC * NT) + c * NT + tc];
        }
    } else {
        for (int j = threadIdx.x; j < 64 * G; j += 256) {
            int pl = j / G, tc = j - pl * G;
            tile[pl * 26 + tc] = mask[(size_t)(p0 + pl) * (NC * NT) + c * NT + t0 + tc];
        }
    }
    __syncthreads();
    for (int j = threadIdx.x; j < 16 * G; j += 256) {
        int p4 = (j & 15) * 4, tc = j >> 4;
        union { __half2 h2[2]; uint2 u; } pk;
        pk.h2[0] = __floats2half2_rn(tile[(p4 + 0) * 26 + tc], tile[(p4 + 1) * 26 + tc]);
        pk.h2[1] = __floats2half2_rn(tile[(p4 + 2) * 26 + tc], tile[(p4 + 3) * 26 + tc]);
        *reinterpret_cast<uint2*>(maskT + (size_t)(c * G + tc) * NPIX + p0 + p4) = pk.u;
    }
}

// FUSED: maskT*kspace + row FFTs (over n). One block = 16 rows of one (c,tc).
// Each wave does 4 rows interleaved (K=4 ILP). Z[q][v][m], m contiguous.
__global__ __launch_bounds__(256) void k_fft_rows(const __half* __restrict__ maskT,
                                                  const __half2* __restrict__ ksS,
                                                  __half2* __restrict__ Z,
                                                  int G) {
    const int q = blockIdx.x;       // c*G + tc
    const int mtile = blockIdx.y;   // 0..19
    const int c = q / G;            // once per block (scalar)
    const int wave = threadIdx.x >> 6;
    const int lane = threadIdx.x & 63;
    const int m0 = mtile * 16;
    __shared__ __half2 tile[NXY * 17];  // [v][16 + 1 pad]
    Tw t;
    tw_init(t);
    const __half2* ks_c = ksS + (size_t)c * NPIX;
    const __half* mk_q = maskT + (size_t)q * NPIX;
    float2 x[4][5], out[4][5];
    #pragma unroll
    for (int k = 0; k < 4; ++k) {
        const int pbase = (m0 + wave + 4 * k) * NXY + lane * 5;
        const __half2* kp = ks_c + pbase;
        const __half* mp = mk_q + pbase;
        #pragma unroll
        for (int r = 0; r < 5; ++r) {
            float2 kv = __half22float2(kp[r]);
            float mkv = __half2float(mp[r]);
            x[k][r] = make_float2(kv.x * mkv, kv.y * mkv);
        }
    }
    fft320xK<4>(t, x, out);
    #pragma unroll
    for (int k = 0; k < 4; ++k) {
        const int mm = wave + 4 * k;
        #pragma unroll
        for (int s5 = 0; s5 < 5; ++s5) {
            int v = t.J + 64 * s5;
            tile[v * 17 + mm] = __floats2half2_rn(out[k][s5].x, out[k][s5].y);
        }
    }
    __syncthreads();
    __half2* dst = Z + (size_t)q * NPIX + m0;
    for (int j = threadIdx.x; j < NXY * 16; j += blockDim.x) {
        int mm = j & 15, v = j >> 4;
        dst[(size_t)v * NXY + mm] = tile[v * 17 + mm];
    }
}

// Column FFTs (over m) + coil combine; K=2 ILP, coils split across blockIdx.z.
__global__ __launch_bounds__(256) void k_fft_cols_combine(const __half2* __restrict__ Z,
                                                          const __half2* __restrict__ smapsP,
                                                          __half2* __restrict__ imtP,
                                                          int t0, int G) {
    const int vtile = blockIdx.x;   // 0..39
    const int tc = blockIdx.y;
    const int half = blockIdx.z;    // 0/1 -> coils [10h, 10h+10)
    const int wave = threadIdx.x >> 6;
    const int lane = threadIdx.x & 63;
    const int v0 = vtile * 8;
    const int vA = v0 + wave;
    const int vB = v0 + 4 + wave;
    __shared__ __half2 tile[NXY * 9];   // [u][8 v + 1 pad]
    Tw t;
    tw_init(t);
    float2 acc[2][5];
    #pragma unroll
    for (int k = 0; k < 2; ++k)
        #pragma unroll
        for (int s5 = 0; s5 < 5; ++s5) acc[k][s5] = make_float2(0.f, 0.f);
    const int c0 = half * 10;
    for (int c = c0; c < c0 + 10; ++c) {
        const __half2* zc = Z + (size_t)(c * G + tc) * NPIX;
        float2 x[2][5], out[2][5];
        const __half2* colA = zc + (size_t)vA * NXY + lane * 5;
        const __half2* colB = zc + (size_t)vB * NXY + lane * 5;
        #pragma unroll
        for (int r = 0; r < 5; ++r) {
            x[0][r] = __half22float2(colA[r]);
            x[1][r] = __half22float2(colB[r]);
        }
        fft320xK<2>(t, x, out);
        const __half2* spA = smapsP + (size_t)((c * NXY + vA) * 5) * 64 + lane;
        const __half2* spB = smapsP + (size_t)((c * NXY + vB) * 5) * 64 + lane;
        #pragma unroll
        for (int s5 = 0; s5 < 5; ++s5) {
            float2 smA = __half22float2(spA[s5 * 64]);
            float2 smB = __half22float2(spB[s5 * 64]);
            float2 ta = cmul(out[0][s5], smA);
            float2 tb = cmul(out[1][s5], smB);
            acc[0][s5].x += ta.x; acc[0][s5].y += ta.y;
            acc[1][s5].x += tb.x; acc[1][s5].y += tb.y;
        }
    }
    #pragma unroll
    for (int s5 = 0; s5 < 5; ++s5) {
        int u = t.J + 64 * s5;
        tile[u * 9 + wave] = __floats2half2_rn(acc[0][s5].x, acc[0][s5].y);
        tile[u * 9 + 4 + wave] = __floats2half2_rn(acc[1][s5].x, acc[1][s5].y);
    }
    __syncthreads();
    __half2* dst = imtP + (size_t)(half * NT + t0 + tc) * NPIX + v0;
    for (int j = threadIdx.x; j < NXY * 8; j += blockDim.x) {
        int vv = j & 7, u = j >> 3;
        dst[(size_t)u * NXY + vv] = tile[u * 9 + vv];
    }
}

// Bilinear warp + sum over t; reduces the two coil-half partials.
__global__ __launch_bounds__(256) void k_warp_sum(const __half2* __restrict__ imtP,
                                                  const float* __restrict__ flow,
                                                  float* __restrict__ out) {
    const int p0 = blockIdx.x * 256;
    const int tid = threadIdx.x;
    __shared__ float s_fl[2 * NT * 257];
    for (int j = tid; j < 256 * 50; j += 256) {
        int pp = j / 50, rem = j - pp * 50;
        int d = rem / 25, tt = rem - d * 25;
        s_fl[(d * NT + tt) * 257 + pp] = flow[(size_t)p0 * 50 + j];
    }
    __syncthreads();
    const int p = p0 + tid;
    const int x = p / NXY, y = p - x * NXY;
    const float fx = (float)x, fy = (float)y;
    float ar = 0.f, ai = 0.f;
    for (int t = 0; t < NT; ++t) {
        float u = s_fl[t * 257 + tid];
        float v = s_fl[(NT + t) * 257 + tid];
        float xs = fminf(fmaxf(fx + u, 0.0f), 319.0f);
        float ys = fminf(fmaxf(fy + v, 0.0f), 319.0f);
        float x0f = floorf(xs), y0f = floorf(ys);
        int x0 = (int)x0f, y0 = (int)y0f;
        int x1 = min(x0 + 1, NXY - 1), y1 = min(y0 + 1, NXY - 1);
        float wx = xs - x0f, wy = ys - y0f;
        const __half2* b0 = imtP + (size_t)t * NPIX;
        const __half2* b1 = imtP + (size_t)(NT + t) * NPIX;
        int i00 = x0 * NXY + y0, i01 = x0 * NXY + y1;
        int i10 = x1 * NXY + y0, i11 = x1 * NXY + y1;
        float2 c00 = __half22float2(b0[i00]); float2 d00 = __half22float2(b1[i00]);
        float2 c01 = __half22float2(b0[i01]); float2 d01 = __half22float2(b1[i01]);
        float2 c10 = __half22float2(b0[i10]); float2 d10 = __half22float2(b1[i10]);
        float2 c11 = __half22float2(b0[i11]); float2 d11 = __half22float2(b1[i11]);
        c00.x += d00.x; c00.y += d00.y;
        c01.x += d01.x; c01.y += d01.y;
        c10.x += d10.x; c10.y += d10.y;
        c11.x += d11.x; c11.y += d11.y;
        float w00 = (1.f - wx) * (1.f - wy), w01 = (1.f - wx) * wy;
        float w10 = wx * (1.f - wy), w11 = wx * wy;
        ar += c00.x * w00 + c01.x * w01 + c10.x * w10 + c11.x * w11;
        ai += c00.y * w00 + c01.y * w01 + c10.y * w10 + c11.y * w11;
    }
    out[p] = ar;
    out[NPIX + p] = ai;
}

extern "C" void kernel_launch(void* const* d_in, const int* in_sizes, int n_in,
                              void* d_out, int out_size, void* d_ws, size_t ws_size,
                              hipStream_t stream) {
    const float* ksr = (const float*)d_in[0];
    const float* ksi = (const float*)d_in[1];
    const float* mask = (const float*)d_in[2];
    const float* smr = (const float*)d_in[3];
    const float* smi = (const float*)d_in[4];
    const float* flow = (const float*)d_in[5];
    float* out = (float*)d_out;

    char* ws = (char*)d_ws;
    const size_t smapsC_bytes = (size_t)NC * NPIX * sizeof(float2);          // 16.4 MB
    const size_t smapsP_bytes = (size_t)NC * NPIX * sizeof(__half2);         // 8.2 MB
    const size_t ksS_bytes = (size_t)NC * NPIX * sizeof(__half2);            // 8.2 MB
    const size_t imtP_bytes = (size_t)2 * NT * NPIX * sizeof(__half2);       // 20.5 MB
    const size_t fixed = smapsC_bytes + smapsP_bytes + ksS_bytes + imtP_bytes;
    // per-t: Z (half2) + maskT (half)
    const size_t per_t = (size_t)NC * NPIX * (sizeof(__half2) + sizeof(__half)); // 12.3 MB

    int G = 1;
    if (ws_size > fixed + per_t) {
        size_t g = (ws_size - fixed) / per_t;
        G = (int)(g > (size_t)NT ? (size_t)NT : g);
    }
    if (G < 1) G = 1;

    float2* smapsC = (float2*)ws;
    __half2* smapsP = (__half2*)(ws + smapsC_bytes);
    __half2* ksS = (__half2*)(ws + smapsC_bytes + smapsP_bytes);
    __half2* imtP = (__half2*)(ws + smapsC_bytes + smapsP_bytes + ksS_bytes);
    __half2* Z = (__half2*)(ws + fixed);
    __half* maskT = (__half*)(ws + fixed + (size_t)NC * G * NPIX * sizeof(__half2));

    k_prep_smaps<<<NPIX / 64, 256, 0, stream>>>(smr, smi, smapsC);
    k_perm_smaps<<<dim3(NC, 5, 5), 256, 0, stream>>>(smapsC, smapsP);
    k_prep_ks<<<NPIX / 64, 256, 0, stream>>>(ksr, ksi, ksS);
    for (int t0 = 0; t0 < NT; t0 += G) {
        int g = (NT - t0) < G ? (NT - t0) : G;
        k_transpose_mask<<<dim3(NPIX / 64, NC), 256, 0, stream>>>(mask, maskT, t0, g);
        k_fft_rows<<<dim3(NC * g, 20), 256, 0, stream>>>(maskT, ksS, Z, g);
        k_fft_cols_combine<<<dim3(40, g, 2), 256, 0, stream>>>(Z, smapsP, imtP, t0, g);
    }
    k_warp_sum<<<NPIX / 256, 256, 0, stream>>>(imtP, flow, out);
}